// Round 10
// baseline (119.193 us; speedup 1.0000x reference)
//
#include <hip/hip_runtime.h>

#define LVL 16
#define FEAT 4
#define HSZ 524288            // 2^19
#define HMASK (HSZ - 1)
#define P1 73856093u
#define P2 19349663u

// ALL 16 levels staged, each padded with a duplicate last entry so that
// e1 = sTab[base+1] always (no clamp, no hash, no branch in main loop)
#define TSTAGE 4195           // sum(res[l]+1)
#define BLOCK 1024
#define ITERS 64              // items/thread; block slab = 65536 items = 1 MiB out
#define LDS_BYTES (TSTAGE * 16)   // 67,120 B -> 2 blocks/CU (134 KB of 160 KB)

typedef float f32x4 __attribute__((ext_vector_type(4)));

// round(np.logspace(log10(16), log10(1024), 16)):
static __device__ __constant__ int kRes[LVL] = {
    16, 21, 28, 37, 49, 64, 84, 111, 147, 194, 256, 338, 446, 588, 776, 1024
};
// exclusive prefix sum of (kRes[l] + 1)  -- padded dense offsets
static __device__ __constant__ int kOffP[LVL] = {
    0, 17, 39, 68, 106, 156, 221, 306, 418, 566, 761, 1018, 1357, 1804, 2393, 3170
};

__global__ void __launch_bounds__(BLOCK)
hashgrid1d_kernel(const float* __restrict__ x,
                  const float* __restrict__ tables,
                  float* __restrict__ out,
                  int B)
{
    extern __shared__ f32x4 sTab[];                // 67,120 B padded dense table

    // ---- stage: de-hash all 16 levels (padded) into dense LDS
    for (int e = threadIdx.x; e < TSTAGE; e += BLOCK) {
        int l = 0;
        #pragma unroll
        for (int k = 1; k < LVL; ++k) l += (e >= kOffP[k]);   // branchless level find
        const int i = min(e - kOffP[l], kRes[l] - 1);         // pad slot dups last
        const unsigned h = (((unsigned)i * P1) ^ ((unsigned)l * P2)) & HMASK;
        sTab[e] = *(const f32x4*)(tables + ((size_t)l * HSZ + h) * FEAT);
    }
    __syncthreads();

    const int t = threadIdx.x;
    // level is loop-invariant (block-iter stride 1024 % 16 == 0)
    const int   l     = t & 15;
    const float resm1 = (float)(kRes[l] - 1);
    const int   soff  = kOffP[l];

    const size_t base_item  = (size_t)blockIdx.x << 16;       // * 65536
    const float* xblk       = x + ((size_t)blockIdx.x << 12); // 4096 points/block

    #pragma unroll 4
    for (int k = 0; k < ITERS; ++k) {
        const int it = (k << 10) + t;              // item within block slab
        const int pl = it >> 4;                    // local point index

        // 16-way redundant read -> 4 cache lines per wave-iter, L1-resident
        const float xc = __builtin_amdgcn_fmed3f(xblk[pl], 0.0f, 1.0f);

        const float tt = xc * resm1;               // fp32, same order as reference
        const float fi = floorf(tt);
        const int   i0 = (int)fi;
        const float w  = tt - fi;

        // uniform: one address, two contiguous ds_read_b128 (pad makes e1 safe)
        const int base = soff + i0;
        const f32x4 e0 = sTab[base];
        const f32x4 e1 = sTab[base + 1];

        const float omw = 1.0f - w;
        const f32x4 r = e0 * omw + e1 * w;

        // block writes a contiguous 1 MiB slab; wave-iter writes 1 KiB contiguous
        *(f32x4*)(out + ((base_item + it) << 2)) = r;
    }
}

extern "C" void kernel_launch(void* const* d_in, const int* in_sizes, int n_in,
                              void* d_out, int out_size, void* d_ws, size_t ws_size,
                              hipStream_t stream)
{
    const float* x      = (const float*)d_in[0];
    const float* tables = (const float*)d_in[1];
    float*       out    = (float*)d_out;
    const int    B      = in_sizes[0];             // 2097152

    const int grid = (B * LVL) / (BLOCK * ITERS);  // 512 blocks -> 2 per CU
    hipLaunchKernelGGL(hashgrid1d_kernel, dim3(grid), dim3(BLOCK),
                       LDS_BYTES, stream, x, tables, out, B);
}

// Round 11
// 101.924 us; speedup vs baseline: 1.1694x; 1.1694x over previous
//
#include <hip/hip_runtime.h>

#define LVL 16
#define FEAT 4
#define HSZ 524288            // 2^19
#define HMASK (HSZ - 1)
#define P1 73856093u
#define P2 19349663u

// ALL 16 levels staged, each padded with a duplicate last entry so that
// e1 = sTab[base+1] always (no clamp, no hash, no branch in main loop)
#define TSTAGE 4195           // sum(res[l]+1)
#define XSTAGE 8192           // points per block (32 KB of x in LDS)
#define BLOCK 1024
#define ITERS 128             // items/thread; block slab = 131072 items = 2 MiB out
#define LDS_BYTES (TSTAGE * 16 + XSTAGE * 4)   // 67120 + 32768 = 99888 B

typedef float f32x4 __attribute__((ext_vector_type(4)));
#define AS1 __attribute__((address_space(1)))
#define AS3 __attribute__((address_space(3)))

// round(np.logspace(log10(16), log10(1024), 16)):
static __device__ __constant__ int kRes[LVL] = {
    16, 21, 28, 37, 49, 64, 84, 111, 147, 194, 256, 338, 446, 588, 776, 1024
};
// exclusive prefix sum of (kRes[l] + 1)  -- padded dense offsets
static __device__ __constant__ int kOffP[LVL] = {
    0, 17, 39, 68, 106, 156, 221, 306, 418, 566, 761, 1018, 1357, 1804, 2393, 3170
};

__global__ void __launch_bounds__(BLOCK)
hashgrid1d_kernel(const float* __restrict__ x,
                  const float* __restrict__ tables,
                  float* __restrict__ out,
                  int B)
{
    extern __shared__ char smem[];
    f32x4* sTab = (f32x4*)smem;                    // 67,120 B padded dense table
    float* sX   = (float*)(smem + TSTAGE * 16);    // 32,768 B x-slab

    // ---- ASYNC stage: all issues in flight, single drain at the barrier.
    // LDS dest per wave = uniform base + lane*16 (e = e0 + tid is consecutive);
    // global src is per-lane (scattered hash addresses) -- HW supports that.
    #pragma unroll
    for (int e0 = 0; e0 < TSTAGE; e0 += BLOCK) {
        const int e = e0 + (int)threadIdx.x;
        if (e < TSTAGE) {
            int l = 0;
            #pragma unroll
            for (int k = 1; k < LVL; ++k) l += (e >= kOffP[k]);   // level find
            const int i = min(e - kOffP[l], kRes[l] - 1);         // pad dups last
            const unsigned h = (((unsigned)i * P1) ^ ((unsigned)l * P2)) & HMASK;
            __builtin_amdgcn_global_load_lds(
                (AS1 const void*)(tables + ((size_t)l * HSZ + h) * FEAT),
                (AS3 void*)(sTab + e), 16, 0, 0);
        }
    }
    // ---- x-slab: 8192 floats, 16 B/lane consecutive -> same async path
    {
        const f32x4* xv = (const f32x4*)x + (size_t)blockIdx.x * (XSTAGE / 4);
        __builtin_amdgcn_global_load_lds((AS1 const void*)(xv + threadIdx.x),
                                         (AS3 void*)(sX + 4 * threadIdx.x), 16, 0, 0);
        __builtin_amdgcn_global_load_lds((AS1 const void*)(xv + threadIdx.x + BLOCK),
                                         (AS3 void*)(sX + 4 * (threadIdx.x + BLOCK)), 16, 0, 0);
    }
    __syncthreads();                               // one vmcnt drain for all 7 issues

    const int t = threadIdx.x;
    // level is loop-invariant (block-iter stride 1024 % 16 == 0)
    const int   l     = t & 15;
    const float resm1 = (float)(kRes[l] - 1);
    const int   soff  = kOffP[l];

    const size_t base_item = (size_t)blockIdx.x << 17;        // * 131072

    #pragma unroll 4
    for (int k = 0; k < ITERS; ++k) {
        const int it = (k << 10) + t;              // item within block slab
        const int pl = it >> 4;                    // local point index

        const float xc = __builtin_amdgcn_fmed3f(sX[pl], 0.0f, 1.0f);

        const float tt = xc * resm1;               // fp32, same order as reference
        const float fi = floorf(tt);
        const int   i0 = (int)fi;
        const float w  = tt - fi;

        // uniform: one address, two contiguous ds_read_b128 (pad makes e1 safe)
        const int base = soff + i0;
        const f32x4 e0 = sTab[base];
        const f32x4 e1 = sTab[base + 1];

        const float omw = 1.0f - w;
        const f32x4 r = e0 * omw + e1 * w;

        // block writes a contiguous 2 MiB slab; wave-iter writes 1 KiB contiguous
        *(f32x4*)(out + ((base_item + it) << 2)) = r;
    }
}

extern "C" void kernel_launch(void* const* d_in, const int* in_sizes, int n_in,
                              void* d_out, int out_size, void* d_ws, size_t ws_size,
                              hipStream_t stream)
{
    const float* x      = (const float*)d_in[0];
    const float* tables = (const float*)d_in[1];
    float*       out    = (float*)d_out;
    const int    B      = in_sizes[0];             // 2097152

    const int grid = (B * LVL) / (BLOCK * ITERS);  // 256 blocks -> 1 per CU
    hipLaunchKernelGGL(hashgrid1d_kernel, dim3(grid), dim3(BLOCK),
                       LDS_BYTES, stream, x, tables, out, B);
}